// Round 8
// baseline (15777.945 us; speedup 1.0000x reference)
//
#include <hip/hip_runtime.h>
#include <hip/hip_bf16.h>

// Problem constants
#define SEQ   4096
#define EMB   256
#define HHID  256      // HH
#define G4    1024     // 4*HH
#define NT    9        // tags
#define TSTART 7
#define TSTOP  8
#define NEGV  (-10000.0f)
#define POISON 0xAAAAAAAAu

// Workspace byte offsets (total ~42.2 MB)
#define WS_XG_F   0u            // 4096*1024 f32 = 16 MB
#define WS_XG_B   16777216u     // 16 MB
#define WS_HF     33554432u     // 4096*256 f32 = 4 MB
#define WS_HB     37748736u     // 4 MB
#define WS_FRAMES 41943040u     // 4096*9 f32 = 147456 B
#define WS_CLAIM  42090496u     // ticket counter (zeroed per launch)

// ---------------------------------------------------------------------------
// Kernel 1: x = embed[sentence]; xg = x @ w_ih^T + b_ih + b_hh  (both dirs)
// ---------------------------------------------------------------------------
__global__ __launch_bounds__(256) void xgate_kernel(
    const int* __restrict__ sentence, const float* __restrict__ embed,
    const float* __restrict__ w_ih_f, const float* __restrict__ b_ih_f,
    const float* __restrict__ b_hh_f,
    const float* __restrict__ w_ih_b, const float* __restrict__ b_ih_b,
    const float* __restrict__ b_hh_b,
    float* __restrict__ xg_f, float* __restrict__ xg_b)
{
    const int st  = blockIdx.x;          // 0..255 (16 s each)
    const int dir = blockIdx.y;
    const float* w  = dir ? w_ih_b : w_ih_f;
    const float* bi = dir ? b_ih_b : b_ih_f;
    const float* bh = dir ? b_hh_b : b_hh_f;
    float* xg = dir ? xg_b : xg_f;
    const int t = threadIdx.x;

    __shared__ float x_t[EMB][16];       // transposed x tile
    for (int sl = 0; sl < 16; ++sl) {
        int s   = st * 16 + sl;
        int tok = sentence[s];
        x_t[t][sl] = embed[(size_t)tok * EMB + t];
    }
    __syncthreads();

    float acc[4][16];
    #pragma unroll
    for (int q = 0; q < 4; ++q)
        #pragma unroll
        for (int sl = 0; sl < 16; ++sl) acc[q][sl] = 0.f;

    #pragma unroll 4
    for (int e = 0; e < EMB; ++e) {
        float w0 = w[(size_t)(t        ) * EMB + e];
        float w1 = w[(size_t)(t + 256  ) * EMB + e];
        float w2 = w[(size_t)(t + 512  ) * EMB + e];
        float w3 = w[(size_t)(t + 768  ) * EMB + e];
        #pragma unroll
        for (int sl = 0; sl < 16; ++sl) {
            float xv = x_t[e][sl];
            acc[0][sl] += w0 * xv;
            acc[1][sl] += w1 * xv;
            acc[2][sl] += w2 * xv;
            acc[3][sl] += w3 * xv;
        }
    }

    #pragma unroll
    for (int q = 0; q < 4; ++q) {
        int g = t + 256 * q;
        float bb = bi[g] + bh[g];
        for (int sl = 0; sl < 16; ++sl) {
            xg[(size_t)(st * 16 + sl) * G4 + g] = acc[q][sl] + bb;
        }
    }
}

// ---------------------------------------------------------------------------
// Kernel 2: bidirectional LSTM recurrence, 16 working blocks pinned to ONE
// XCD (HW_REG_XCC_ID + ticket claim; extra blocks exit; claimers are
// co-resident by construction so no deadlock).
//
// Sync: data-as-flag poison scheme (hf/hb pre-poisoned 0xAAAAAAAA).
// Producer: dual store — sc0 (XCD-local L2 fast path) + sc1 (agent/IF,
// the R2-R5-proven guaranteed path). Consumer: hybrid poll — 7/8 iters
// opportunistic sc0 load (fast if L2-hit, harmless if L1-stale), every 8th
// iter an agent-scope atomic load (guaranteed forward progress). Cannot hang.
//
// Thread t = (unit rb=t>>3, col-block cb=t&7). 128 weights/thread in AGPRs
// (v_accvgpr_write/read). 8-lane shfl_xor reduce; lane cb==0 does
// activations + state. xg prefetched 3 steps ahead (rotation mod 4).
// ---------------------------------------------------------------------------
__global__ __launch_bounds__(256, 1) void lstm_kernel(
    const float* __restrict__ xg_f, const float* __restrict__ xg_b,
    const float* __restrict__ w_hh_f, const float* __restrict__ w_hh_b,
    const float* __restrict__ h0, const float* __restrict__ c0,
    float* __restrict__ hf, float* __restrict__ hb,
    unsigned int* __restrict__ claim)
{
    // --- role claim: first 16 blocks observed on XCD 0 take the work ---
    unsigned int xcc;
    asm volatile("s_getreg_b32 %0, hwreg(HW_REG_XCC_ID)" : "=s"(xcc));
    __shared__ int role_s;
    if (threadIdx.x == 0) {
        int role = -1;
        if (xcc == 0u) {
            unsigned int slot = atomicAdd(claim, 1u);   // device-scope
            if (slot < 16u) role = (int)slot;
        }
        role_s = role;
    }
    __syncthreads();
    const int role = role_s;
    if (role < 0) return;

    const int dir   = role >> 3;
    const int slice = role & 7;
    const int t     = threadIdx.x;
    const int cb    = t & 7;          // col block: h cols cb*32 .. cb*32+31
    const int rb    = t >> 3;         // unit within slice (0..31)
    const int unit  = slice * 32 + rb;

    const float* xg   = dir ? xg_b  : xg_f;
    const float* w_hh = dir ? w_hh_b : w_hh_f;
    float* hout = dir ? hb : hf;

    __shared__ float buf[2][HHID];    // h ping-pong

    // --- weights into AGPRs: wa[q*32+j] = W[q*256+unit][cb*32+j] ---
    float wa[128];
    #pragma unroll
    for (int q = 0; q < 4; ++q) {
        #pragma unroll
        for (int j = 0; j < 32; ++j) {
            float tmp = w_hh[(size_t)(q * HHID + unit) * HHID + cb * 32 + j];
            asm volatile("v_accvgpr_write_b32 %0, %1"
                         : "=a"(wa[q * 32 + j]) : "v"(tmp));
        }
    }

    float c_reg = 0.f;
    if (cb == 0) c_reg = c0[dir * HHID + unit];

    const bool own = (t >= slice * 32) && (t < slice * 32 + 32);

    // xg prefetch rotation (depth 3, slots mod 4); preload steps 0,1,2
    float xgb[4][4];
    #pragma unroll
    for (int b = 0; b < 4; ++b)
        #pragma unroll
        for (int j = 0; j < 4; ++j) xgb[b][j] = 0.f;
    if (cb == 0) {
        #pragma unroll
        for (int m = 0; m < 3; ++m) {
            const int sm = dir ? (SEQ - 1 - m) : m;
            const float* xb = xg + (size_t)sm * G4 + unit;
            xgb[m][0] = xb[0];
            xgb[m][1] = xb[HHID];
            xgb[m][2] = xb[2 * HHID];
            xgb[m][3] = xb[3 * HHID];
        }
    }

    for (int nb = 0; nb < SEQ; nb += 4) {
        #pragma unroll
        for (int u = 0; u < 4; ++u) {
            const int n = nb + u;
            const int s = dir ? (SEQ - 1 - n) : n;

            // Acquire h_prev word t (own 32 words arrive via LDS shortcut)
            if (n == 0) {
                buf[0][t] = h0[dir * HHID + t];
            } else if (!own) {
                const int sp = dir ? (s + 1) : (s - 1);
                const unsigned int* src =
                    (const unsigned int*)(hout + (size_t)sp * HHID) + t;
                unsigned int v;
                int k = 0;
                while (true) {
                    if ((k & 7) == 7) {
                        // guaranteed-progress flavor (proven R2-R5 path)
                        v = __hip_atomic_load(src, __ATOMIC_RELAXED,
                                              __HIP_MEMORY_SCOPE_AGENT);
                    } else {
                        // opportunistic XCD-L2 flavor
                        asm volatile(
                            "global_load_dword %0, %1, off sc0\n\t"
                            "s_waitcnt vmcnt(0)"
                            : "=v"(v) : "v"(src) : "memory");
                    }
                    ++k;
                    if (v != POISON) break;
                }
                buf[u & 1][t] = __uint_as_float(v);
            }

            // Prefetch xg for step n+3 (post-poll; ~3 steps of slack before
            // any vmcnt(0) drain can expose its HBM latency)
            {
                const int m = n + 3;
                if (cb == 0 && m < SEQ) {
                    const int sm = dir ? (SEQ - 1 - m) : m;
                    const float* xb = xg + (size_t)sm * G4 + unit;
                    float* d = xgb[(u + 3) & 3];
                    d[0] = xb[0];
                    d[1] = xb[HHID];
                    d[2] = xb[2 * HHID];
                    d[3] = xb[3 * HHID];
                }
            }
            __syncthreads();

            // 32-col partial dot for 4 gates (accvgpr_read + fmac)
            float a0 = 0.f, a1 = 0.f, a2 = 0.f, a3 = 0.f;
            const float4* h4 = (const float4*)(&buf[u & 1][cb * 32]);
            #pragma unroll
            for (int j4 = 0; j4 < 8; ++j4) {
                float4 hv = h4[j4];
                #pragma unroll
                for (int k = 0; k < 4; ++k) {
                    float hk = (k == 0) ? hv.x : (k == 1) ? hv.y
                             : (k == 2) ? hv.z : hv.w;
                    float w0, w1, w2, w3;
                    asm volatile("v_accvgpr_read_b32 %0, %1"
                                 : "=v"(w0) : "a"(wa[0 * 32 + j4 * 4 + k]));
                    asm volatile("v_accvgpr_read_b32 %0, %1"
                                 : "=v"(w1) : "a"(wa[1 * 32 + j4 * 4 + k]));
                    asm volatile("v_accvgpr_read_b32 %0, %1"
                                 : "=v"(w2) : "a"(wa[2 * 32 + j4 * 4 + k]));
                    asm volatile("v_accvgpr_read_b32 %0, %1"
                                 : "=v"(w3) : "a"(wa[3 * 32 + j4 * 4 + k]));
                    a0 += w0 * hk;
                    a1 += w1 * hk;
                    a2 += w2 * hk;
                    a3 += w3 * hk;
                }
            }

            // 8-lane butterfly reduce across col blocks
            #pragma unroll
            for (int m = 1; m <= 4; m <<= 1) {
                a0 += __shfl_xor(a0, m);
                a1 += __shfl_xor(a1, m);
                a2 += __shfl_xor(a2, m);
                a3 += __shfl_xor(a3, m);
            }

            // Lane cb==0: activations, state, dual-flavor h store
            if (cb == 0) {
                float gi = a0 + xgb[u][0];
                float gf = a1 + xgb[u][1];
                float gg = a2 + xgb[u][2];
                float go = a3 + xgb[u][3];
                float iv = 1.f / (1.f + __expf(-gi));
                float fv = 1.f / (1.f + __expf(-gf));
                float gv = 1.f - 2.f / (__expf(2.f * gg) + 1.f);   // tanh
                float ov = 1.f / (1.f + __expf(-go));
                float c  = fv * c_reg + iv * gv;
                c_reg = c;
                float h  = ov * (1.f - 2.f / (__expf(2.f * c) + 1.f));
                unsigned int hbits = __float_as_uint(h);
                unsigned int* dst =
                    (unsigned int*)(hout + (size_t)s * HHID) + unit;
                asm volatile(
                    "global_store_dword %0, %1, off sc0\n\t"
                    "global_store_dword %0, %1, off sc1"
                    :: "v"(dst), "v"(hbits) : "memory");
                buf[(u + 1) & 1][unit] = h;   // local shortcut for next step
            }
            // No second barrier: producer writes target buf[(n+1)&1], this
            // step's readers use buf[n&1]; next iteration's barrier orders it.
        }
    }
}

// ---------------------------------------------------------------------------
// Kernel 3: frames = [hf|hb] @ W_out^T + b_out      (4096 x 9)
// ---------------------------------------------------------------------------
__global__ __launch_bounds__(256) void frames_kernel(
    const float* __restrict__ hf, const float* __restrict__ hb,
    const float* __restrict__ W_out, const float* __restrict__ b_out,
    float* __restrict__ frames)
{
    int o = blockIdx.x * 256 + threadIdx.x;
    if (o >= SEQ * NT) return;
    int s = o / NT;
    int j = o - s * NT;
    const float4* a0 = (const float4*)(hf + (size_t)s * HHID);
    const float4* a1 = (const float4*)(hb + (size_t)s * HHID);
    const float4* w0 = (const float4*)(W_out + (size_t)j * 512);
    const float4* w1 = w0 + 64;
    float acc = 0.f;
    #pragma unroll 8
    for (int i = 0; i < 64; ++i) {
        float4 a = a0[i], b = w0[i];
        acc += a.x * b.x + a.y * b.y + a.z * b.z + a.w * b.w;
        float4 c = a1[i], d = w1[i];
        acc += c.x * d.x + c.y * d.y + c.z * d.z + c.w * d.w;
    }
    frames[o] = acc + b_out[j];
}

// ---------------------------------------------------------------------------
// Kernel 4: fused CRF forward + backtrack. ONE wave (64 threads), no inner-
// loop barriers. Per-lane alpha; __shfl always executed by ALL lanes.
// Backpointers in LDS; t0 backtracks and writes tags to dout. Score->dout[0].
// ---------------------------------------------------------------------------
__global__ __launch_bounds__(64) void crf_kernel(
    const float* __restrict__ frames, const float* __restrict__ trans,
    float* __restrict__ dout)
{
    __shared__ float fr[512 * NT];                 // 18432 B chunk of frames
    __shared__ unsigned char bpl[SEQ * NT];        // 36864 B backpointers
    const int t = threadIdx.x;
    const int tc = (t < NT) ? t : 0;               // clamped lane for fr reads

    float trow[NT];
    #pragma unroll
    for (int i = 0; i < NT; ++i) trow[i] = 0.f;
    if (t < NT) {
        #pragma unroll
        for (int i = 0; i < NT; ++i) trow[i] = trans[i * NT + t];
    }
    float alpha = (t == TSTART) ? 0.f : NEGV;      // lane t holds alpha[t]

    for (int chunk = 0; chunk < 8; ++chunk) {
        for (int idx = t; idx < 512 * NT; idx += 64)
            fr[idx] = frames[chunk * 512 * NT + idx];
        __syncthreads();   // single wave: cheap

        for (int sl = 0; sl < 512; ++sl) {
            const int s = chunk * 512 + sl;
            float v[NT];
            #pragma unroll
            for (int i = 0; i < NT; ++i)
                v[i] = __shfl(alpha, i) + trow[i];     // all lanes active
            float mx = v[0];
            int   am = 0;
            #pragma unroll
            for (int i = 1; i < NT; ++i)
                if (v[i] > mx) { mx = v[i]; am = i; }
            float sum = 0.f;
            #pragma unroll
            for (int i = 0; i < NT; ++i) sum += __expf(v[i] - mx);
            float anew = fr[sl * NT + tc] + mx + __logf(sum);
            if (t < NT) {
                bpl[s * NT + t] = (unsigned char)am;
                alpha = anew;
            }
        }
        __syncthreads();
    }

    // final: fin[j] = alpha[j] + trans[j, STOP]; gather with ALL lanes active
    float fin = NEGV;
    if (t < NT) fin = alpha + trans[t * NT + TSTOP];
    float f[NT];
    #pragma unroll
    for (int j = 0; j < NT; ++j) f[j] = __shfl(fin, j);  // all lanes active

    if (t == 0) {
        float mx = f[0];
        int best = 0;
        #pragma unroll
        for (int j = 1; j < NT; ++j)
            if (f[j] > mx) { mx = f[j]; best = j; }
        float sum = 0.f;
        #pragma unroll
        for (int j = 0; j < NT; ++j) sum += __expf(f[j] - mx);
        dout[0] = mx + __logf(sum);

        // backtrack entirely from LDS, stream tags straight to dout
        int cur = best;
        dout[1 + SEQ - 1] = (float)cur;
        for (int s = SEQ - 2; s >= 0; --s) {
            cur = bpl[(s + 1) * NT + cur];
            dout[1 + s] = (float)cur;
        }
    }
}

// ---------------------------------------------------------------------------
extern "C" void kernel_launch(void* const* d_in, const int* in_sizes, int n_in,
                              void* d_out, int out_size, void* d_ws, size_t ws_size,
                              hipStream_t stream)
{
    const int*   sentence = (const int*)  d_in[0];
    const float* embed    = (const float*)d_in[1];
    const float* w_ih_f   = (const float*)d_in[2];
    const float* w_hh_f   = (const float*)d_in[3];
    const float* b_ih_f   = (const float*)d_in[4];
    const float* b_hh_f   = (const float*)d_in[5];
    const float* w_ih_b   = (const float*)d_in[6];
    const float* w_hh_b   = (const float*)d_in[7];
    const float* b_ih_b   = (const float*)d_in[8];
    const float* b_hh_b   = (const float*)d_in[9];
    const float* h0       = (const float*)d_in[10];
    const float* c0       = (const float*)d_in[11];
    const float* W_out    = (const float*)d_in[12];
    const float* b_out    = (const float*)d_in[13];
    const float* trans    = (const float*)d_in[14];

    float* out = (float*)d_out;
    char*  ws  = (char*)d_ws;

    float* xg_f   = (float*)(ws + WS_XG_F);
    float* xg_b   = (float*)(ws + WS_XG_B);
    float* hf     = (float*)(ws + WS_HF);
    float* hb     = (float*)(ws + WS_HB);
    float* frames = (float*)(ws + WS_FRAMES);
    unsigned int* claim = (unsigned int*)(ws + WS_CLAIM);

    // hf/hb -> poison sentinel (contiguous: one 8 MB memset); claim -> 0
    hipMemsetAsync(hf, 0xAA, 2u * SEQ * HHID * sizeof(float), stream);
    hipMemsetAsync(claim, 0, 256, stream);

    xgate_kernel<<<dim3(256, 2), 256, 0, stream>>>(
        sentence, embed, w_ih_f, b_ih_f, b_hh_f, w_ih_b, b_ih_b, b_hh_b,
        xg_f, xg_b);

    lstm_kernel<<<2048, 256, 0, stream>>>(
        xg_f, xg_b, w_hh_f, w_hh_b, h0, c0, hf, hb, claim);

    frames_kernel<<<(SEQ * NT + 255) / 256, 256, 0, stream>>>(
        hf, hb, W_out, b_out, frames);

    crf_kernel<<<1, 64, 0, stream>>>(frames, trans, out);
}